// Round 8
// baseline (159.366 us; speedup 1.0000x reference)
//
#include <hip/hip_runtime.h>
#include <hip/hip_bf16.h>

// ---------------------------------------------------------------------------
// EuclideanDeconf: out[b,c] = (2*dot(x[b],W[c]) - ||x[b]||^2 - ||W[c]||^2) / D
// R8: BARRIER-FREE K-loop. Each wave owns a private 2x8KB ping-pong LDS
// staging region (its 64-row A-half + 64-col B-half) -> only same-wave
// ds ordering (lgkmcnt) is needed; zero s_barrier between K-iters. Waves are
// independent software pipelines. fp8 e4m3 (x32), 128x128xBK64, split-K=2,
// fp8 partials (1/32) + reduce pass.
// ---------------------------------------------------------------------------

typedef float f32x4 __attribute__((ext_vector_type(4)));
typedef float f32x2 __attribute__((ext_vector_type(2)));
typedef long long2_t __attribute__((ext_vector_type(2)));

#define BDIM 4096
#define DDIM 4096
#define CDIM 1024
#define TM 128
#define TN 128
#define BK 64
#define KSPLIT 2
#define NIT ((DDIM / KSPLIT) / BK)   // 32
#define SCALE 32.0f
#define INV_SS (1.0f/1024.0f)
#define PSCALE (1.0f/32.0f)          // partial pack scale
#define PS_INV 32.0f

// One WAVE per row: fp32 row -> fp8(e4m3, x SCALE) row + fp32 sum-of-squares
// (of the UNSCALED values).
__global__ __launch_bounds__(256) void cvt_rowsq(
    const float* __restrict__ x, const float* __restrict__ W,
    unsigned char* __restrict__ xb, unsigned char* __restrict__ wb,
    float* __restrict__ xsq, float* __restrict__ wsq)
{
    const int lane = threadIdx.x & 63;
    const int row = blockIdx.x * 4 + (threadIdx.x >> 6);

    const float* src;
    unsigned char* dst;
    float* sq;
    if (row < BDIM) {
        src = x + (size_t)row * DDIM;
        dst = xb + (size_t)row * DDIM;
        sq = xsq + row;
    } else {
        int r = row - BDIM;
        src = W + (size_t)r * DDIM;
        dst = wb + (size_t)r * DDIM;
        sq = wsq + r;
    }

    const float4* s4 = (const float4*)src;
    unsigned int* d4 = (unsigned int*)dst;
    float a = 0.f;
    #pragma unroll
    for (int s = 0; s < DDIM / 4 / 64; ++s) {
        float4 f = s4[lane + 64 * s];
        a += f.x * f.x + f.y * f.y + f.z * f.z + f.w * f.w;
        unsigned int p = 0;
        p = __builtin_amdgcn_cvt_pk_fp8_f32(f.x * SCALE, f.y * SCALE, p, false);
        p = __builtin_amdgcn_cvt_pk_fp8_f32(f.z * SCALE, f.w * SCALE, p, true);
        d4[lane + 64 * s] = p;
    }
    #pragma unroll
    for (int off = 32; off > 0; off >>= 1) a += __shfl_down(a, off);
    if (lane == 0) *sq = a;
}

// --- GEMM ---
// Per-wave LDS region: sm[wid][buf][8192]: A-half 64 rows x 64B at +0,
// B-half at +4096. Row layout swizzled (slot = chunk ^ (row&3)), frag reads
// are ds_read_b128, conflict-free (2 lanes/bank).
struct Pref { long2_t a[4], b[4]; };

__global__ __launch_bounds__(256, 2) void gemm_eucl(
    const unsigned char* __restrict__ xb,   // [B, D] fp8
    const unsigned char* __restrict__ wb,   // [C, D] fp8
    unsigned int* __restrict__ part)        // [KSPLIT][256 blk][16 frag][256]
{
    __shared__ unsigned char sm[4][2][8192];   // 64 KB

    const int tid = threadIdx.x;
    const int lane = tid & 63;
    const int wid = tid >> 6;
    const int bm = blockIdx.x * TM;
    const int bn = blockIdx.y * TN;
    const int ks = blockIdx.z * (DDIM / KSPLIT);
    const int wm = (wid >> 1) * 64;
    const int wn = (wid & 1) * 64;

    // staging: lane l handles rows lr+16q (q=0..3), 16B chunk c per row
    const int lr = lane >> 2, c = lane & 3;
    const unsigned char* gA[4];
    const unsigned char* gB[4];
    #pragma unroll
    for (int q = 0; q < 4; ++q) {
        gA[q] = xb + (size_t)(bm + wm + lr + 16 * q) * DDIM + ks + c * 16;
        gB[q] = wb + (size_t)(bn + wn + lr + 16 * q) * DDIM + ks + c * 16;
    }

    unsigned char* mybuf = &sm[wid][0][0];
    // LDS write offset: row r=lr+16q, slot = c ^ (r&3) (q-invariant since 16q%4==0)
    const int wbase = lr * 64 + ((c ^ (lr & 3)) * 16);   // + q*1024; B at +4096

    // fragment read offsets (LOCAL rows within the wave's 64-row/col halves)
    const int kc = lane >> 4;
    const int ml = lane & 15;
    int aoff[4], boff[4];
    #pragma unroll
    for (int i = 0; i < 4; ++i) {
        int r = i * 16 + ml;
        aoff[i] = r * 64 + ((kc ^ (r & 3)) * 16);
        boff[i] = 4096 + aoff[i];
    }

    f32x4 acc[4][4] = {};

#define LOADSET(S, KT)                                                    \
    do {                                                                  \
        _Pragma("unroll")                                                 \
        for (int q = 0; q < 4; ++q) {                                     \
            (S).a[q] = *(const long2_t*)(gA[q] + (KT) * BK);              \
            (S).b[q] = *(const long2_t*)(gB[q] + (KT) * BK);              \
        }                                                                 \
    } while (0)

#define WRITESET(buf, S)                                                  \
    do {                                                                  \
        unsigned char* d = mybuf + (buf) * 8192 + wbase;                  \
        _Pragma("unroll")                                                 \
        for (int q = 0; q < 4; ++q) {                                     \
            *(long2_t*)(d + q * 1024) = (S).a[q];                         \
            *(long2_t*)(d + q * 1024 + 4096) = (S).b[q];                  \
        }                                                                 \
    } while (0)

#define MFMA8(LA, I)                                                      \
    do {                                                                  \
        _Pragma("unroll")                                                 \
        for (int j = 0; j < 4; ++j) {                                     \
            acc[I][j] = __builtin_amdgcn_mfma_f32_16x16x32_fp8_fp8(       \
                (LA).x, lb[j].x, acc[I][j], 0, 0, 0);                     \
            acc[I][j] = __builtin_amdgcn_mfma_f32_16x16x32_fp8_fp8(       \
                (LA).y, lb[j].y, acc[I][j], 0, 0, 0);                     \
        }                                                                 \
    } while (0)

#define COMPUTE(buf)                                                      \
    do {                                                                  \
        const unsigned char* s = mybuf + (buf) * 8192;                    \
        long2_t lb[4];                                                    \
        _Pragma("unroll")                                                 \
        for (int j = 0; j < 4; ++j) lb[j] = *(const long2_t*)(s + boff[j]); \
        long2_t laA = *(const long2_t*)(s + aoff[0]);                     \
        long2_t laB = *(const long2_t*)(s + aoff[1]);                     \
        MFMA8(laA, 0);                                                    \
        laA = *(const long2_t*)(s + aoff[2]);                             \
        MFMA8(laB, 1);                                                    \
        laB = *(const long2_t*)(s + aoff[3]);                             \
        MFMA8(laA, 2);                                                    \
        MFMA8(laB, 3);                                                    \
    } while (0)

    Pref S;
    LOADSET(S, 0);
    WRITESET(0, S);
    // NO barriers: each wave's pipeline is private; lgkmcnt orders its own
    // ds_write(k) -> ds_read(k); global loads for k+1 stay in flight under
    // COMPUTE(k) and are consumed by WRITESET after it.
    #pragma unroll 2
    for (int k = 0; k < NIT - 1; ++k) {
        LOADSET(S, k + 1);
        COMPUTE(k & 1);
        WRITESET((k + 1) & 1, S);
    }
    COMPUTE((NIT - 1) & 1);

    // fp8 partials (x 1/32): 1 uint per frag per thread, fully coalesced.
    unsigned int* p = part
        + (((size_t)blockIdx.z * 256 + (blockIdx.x * 8 + blockIdx.y)) * 16) * 256;
    #pragma unroll
    for (int i = 0; i < 4; ++i)
        #pragma unroll
        for (int j = 0; j < 4; ++j) {
            unsigned int pk = 0;
            pk = __builtin_amdgcn_cvt_pk_fp8_f32(
                acc[i][j][0] * PSCALE, acc[i][j][1] * PSCALE, pk, false);
            pk = __builtin_amdgcn_cvt_pk_fp8_f32(
                acc[i][j][2] * PSCALE, acc[i][j][3] * PSCALE, pk, true);
            p[(i * 4 + j) * 256 + tid] = pk;
        }
#undef LOADSET
#undef WRITESET
#undef MFMA8
#undef COMPUTE
}

// 512 blocks; block handles 8 frags of one gemm-block. Sums KSPLIT slices
// (fp8 unpack), applies epilogue, scatters to out.
__global__ __launch_bounds__(256) void reduce_out(
    const unsigned int* __restrict__ part, const float* __restrict__ xsq,
    const float* __restrict__ wsq, float* __restrict__ out)
{
    const int bid = blockIdx.x;           // 0..511
    const int bb = bid >> 1;              // gemm block (bx*8 + by)
    const int f0 = (bid & 1) * 8;
    const int t = threadIdx.x;
    const int lane = t & 63;
    const int wid = t >> 6;
    const int bm = (bb >> 3) * TM, bn = (bb & 7) * TN;
    const int wm = (wid >> 1) * 64, wn = (wid & 1) * 64;
    const int row_l = (lane >> 4) * 4, col_l = lane & 15;
    const size_t sl = (size_t)256 * 16 * 256;   // uints per slice
    const float c1 = 2.0f * PS_INV * INV_SS / (float)DDIM;
    const float c2 = 1.0f / (float)DDIM;

    #pragma unroll
    for (int f = f0; f < f0 + 8; ++f) {
        size_t o = ((size_t)bb * 16 + f) * 256 + t;
        f32x2 s01 = {0.f, 0.f}, s23 = {0.f, 0.f};
        #pragma unroll
        for (int z = 0; z < KSPLIT; ++z) {
            unsigned int u = part[o + (size_t)z * sl];
            s01 += __builtin_amdgcn_cvt_pk_f32_fp8(u, false);
            s23 += __builtin_amdgcn_cvt_pk_f32_fp8(u, true);
        }
        int i = f >> 2, j = f & 3;
        int gn = bn + wn + j * 16 + col_l;
        float wv = wsq[gn];
        float sv[4] = {s01.x, s01.y, s23.x, s23.y};
        #pragma unroll
        for (int r = 0; r < 4; ++r) {
            int gm = bm + wm + i * 16 + row_l + r;
            out[(size_t)gm * CDIM + gn] = sv[r] * c1 - (xsq[gm] + wv) * c2;
        }
    }
}

// --- Fallback: naive fp32 (any ws) ---
__global__ void fallback_kernel(const float* __restrict__ x, const float* __restrict__ W,
                                float* __restrict__ out)
{
    int c = blockIdx.x * blockDim.x + threadIdx.x;
    int b = blockIdx.y;
    if (c >= CDIM) return;
    const float* xr = x + (size_t)b * DDIM;
    const float* wr = W + (size_t)c * DDIM;
    float xs = 0.f, ws = 0.f, cr = 0.f;
    for (int d = 0; d < DDIM; ++d) {
        float xv = xr[d], wv = wr[d];
        xs += xv * xv; ws += wv * wv; cr += xv * wv;
    }
    out[(size_t)b * CDIM + c] = (2.0f * cr - xs - ws) / (float)DDIM;
}

extern "C" void kernel_launch(void* const* d_in, const int* in_sizes, int n_in,
                              void* d_out, int out_size, void* d_ws, size_t ws_size,
                              hipStream_t stream) {
    const float* x = (const float*)d_in[0];   // [B, D] fp32
    const float* W = (const float*)d_in[1];   // [C, D] fp32
    float* out = (float*)d_out;               // [B, C] fp32

    size_t need = (size_t)(BDIM + CDIM) * DDIM                 // fp8 inputs 20 MB
                + (size_t)(BDIM + CDIM) * sizeof(float)        // norms
                + (size_t)KSPLIT * BDIM * CDIM;                // fp8 partials 8 MB
    if (ws_size < need) {
        fallback_kernel<<<dim3(CDIM / 256, BDIM), 256, 0, stream>>>(x, W, out);
        return;
    }

    unsigned char* xb = (unsigned char*)d_ws;              // 16 MB
    unsigned char* wb = xb + (size_t)BDIM * DDIM;          // 4 MB
    float* xsq = (float*)(wb + (size_t)CDIM * DDIM);       // 16 KB
    float* wsq = xsq + BDIM;                               // 4 KB
    unsigned int* part = (unsigned int*)(wsq + CDIM);      // 8 MB

    cvt_rowsq<<<(BDIM + CDIM) / 4, 256, 0, stream>>>(x, W, xb, wb, xsq, wsq);
    gemm_eucl<<<dim3(BDIM / TM, CDIM / TN, KSPLIT), 256, 0, stream>>>(xb, wb, part);
    reduce_out<<<512, 256, 0, stream>>>(part, xsq, wsq, out);
}

// Round 9
// 153.511 us; speedup vs baseline: 1.0381x; 1.0381x over previous
//
#include <hip/hip_runtime.h>
#include <hip/hip_bf16.h>

// ---------------------------------------------------------------------------
// EuclideanDeconf: out[b,c] = (2*dot(x[b],W[c]) - ||x[b]||^2 - ||W[c]||^2) / D
// R9: 2-wave blocks (128 thr), tile 64x128xBK64 — minimal barrier coupling
// (2 waves) + ~6 independent block-pipelines/CU (24KB LDS). PD=2 register
// prefetch ring, lgkm-only barrier. fp8 e4m3 (x32) staging, split-K=4,
// fp8 partials (1/16) + reduce pass.
// ---------------------------------------------------------------------------

typedef float f32x4 __attribute__((ext_vector_type(4)));
typedef float f32x2 __attribute__((ext_vector_type(2)));
typedef long long2_t __attribute__((ext_vector_type(2)));

#define BDIM 4096
#define DDIM 4096
#define CDIM 1024
#define TM 64
#define TN 128
#define BK 64
#define KSPLIT 4
#define NIT ((DDIM / KSPLIT) / BK)   // 16
#define SCALE 32.0f
#define INV_SS (1.0f/1024.0f)
#define PSCALE 0.0625f               // partial pack scale (1/16)
#define PS_INV 16.0f

// lgkm-only barrier: ds_writes drained; register prefetch loads stay in flight.
#define SYNC_LGKM() asm volatile("s_waitcnt lgkmcnt(0)\n\ts_barrier" ::: "memory")

// One WAVE per row: fp32 row -> fp8(e4m3, x SCALE) row + fp32 sum-of-squares
// (of the UNSCALED values).
__global__ __launch_bounds__(256) void cvt_rowsq(
    const float* __restrict__ x, const float* __restrict__ W,
    unsigned char* __restrict__ xb, unsigned char* __restrict__ wb,
    float* __restrict__ xsq, float* __restrict__ wsq)
{
    const int lane = threadIdx.x & 63;
    const int row = blockIdx.x * 4 + (threadIdx.x >> 6);

    const float* src;
    unsigned char* dst;
    float* sq;
    if (row < BDIM) {
        src = x + (size_t)row * DDIM;
        dst = xb + (size_t)row * DDIM;
        sq = xsq + row;
    } else {
        int r = row - BDIM;
        src = W + (size_t)r * DDIM;
        dst = wb + (size_t)r * DDIM;
        sq = wsq + r;
    }

    const float4* s4 = (const float4*)src;
    unsigned int* d4 = (unsigned int*)dst;
    float a = 0.f;
    #pragma unroll
    for (int s = 0; s < DDIM / 4 / 64; ++s) {
        float4 f = s4[lane + 64 * s];
        a += f.x * f.x + f.y * f.y + f.z * f.z + f.w * f.w;
        unsigned int p = 0;
        p = __builtin_amdgcn_cvt_pk_fp8_f32(f.x * SCALE, f.y * SCALE, p, false);
        p = __builtin_amdgcn_cvt_pk_fp8_f32(f.z * SCALE, f.w * SCALE, p, true);
        d4[lane + 64 * s] = p;
    }
    #pragma unroll
    for (int off = 32; off > 0; off >>= 1) a += __shfl_down(a, off);
    if (lane == 0) *sq = a;
}

// --- GEMM ---
// LDS layout (verified R5-R7): elem (row m, kc, k2, j) at byte
// m*64 + ((kc ^ (m&3))*16) + k2*8 + j. Fragment reads: ds_read_b128.
// Block = 2 waves; wave w computes rows 0..63 x cols w*64..w*64+63.
struct Pref { long2_t a[2], b[4]; };

__global__ __launch_bounds__(128, 3) void gemm_eucl(
    const unsigned char* __restrict__ xb,   // [B, D] fp8
    const unsigned char* __restrict__ wb,   // [C, D] fp8
    unsigned int* __restrict__ part)        // [KSPLIT][512 tile][2 wid][16f][64]
{
    __shared__ unsigned char sm[2][12288];  // 24 KB: A 4KB + B 8KB per buf

    const int tid = threadIdx.x;            // 0..127
    const int lane = tid & 63;
    const int wid = tid >> 6;               // 0..1
    const int bm = blockIdx.x * TM;
    const int bn = blockIdx.y * TN;
    const int ks = blockIdx.z * (DDIM / KSPLIT);

    // staging: pass-based, 4 lanes per 64B row (coalesced 64B per 4 lanes).
    // A: 2 passes (rows p*32 + t>>2), B: 4 passes.
    const int sr = tid >> 2, sc = tid & 3;
    const unsigned char* gA[2];
    const unsigned char* gB[4];
    #pragma unroll
    for (int p = 0; p < 2; ++p)
        gA[p] = xb + (size_t)(bm + p * 32 + sr) * DDIM + ks + sc * 16;
    #pragma unroll
    for (int p = 0; p < 4; ++p)
        gB[p] = wb + (size_t)(bn + p * 32 + sr) * DDIM + ks + sc * 16;

    // LDS write offsets: row r = p*32+sr, slot = sc ^ (r&3); r&3 == sr&3.
    const int woA = sr * 64 + ((sc ^ (sr & 3)) * 16);       // + p*2048
    const int woB = 4096 + woA;                              // + p*2048

    // fragment read offsets
    const int kc = lane >> 4;
    const int ml = lane & 15;
    int aoff[4], boff[4];
    #pragma unroll
    for (int i = 0; i < 4; ++i) {
        int r = i * 16 + ml;
        aoff[i] = r * 64 + ((kc ^ (r & 3)) * 16);
        int rb = wid * 64 + i * 16 + ml;
        boff[i] = 4096 + rb * 64 + ((kc ^ (rb & 3)) * 16);
    }

    f32x4 acc[4][4] = {};

#define LOADSET(S, KT)                                                    \
    do {                                                                  \
        _Pragma("unroll")                                                 \
        for (int p = 0; p < 2; ++p)                                       \
            (S).a[p] = *(const long2_t*)(gA[p] + (KT) * BK);              \
        _Pragma("unroll")                                                 \
        for (int p = 0; p < 4; ++p)                                       \
            (S).b[p] = *(const long2_t*)(gB[p] + (KT) * BK);              \
    } while (0)

#define WRITESET(buf, S)                                                  \
    do {                                                                  \
        unsigned char* d = &sm[buf][0];                                   \
        _Pragma("unroll")                                                 \
        for (int p = 0; p < 2; ++p)                                       \
            *(long2_t*)(d + woA + p * 2048) = (S).a[p];                   \
        _Pragma("unroll")                                                 \
        for (int p = 0; p < 4; ++p)                                       \
            *(long2_t*)(d + woB + p * 2048) = (S).b[p];                   \
    } while (0)

#define MFMA8(LA, I)                                                      \
    do {                                                                  \
        _Pragma("unroll")                                                 \
        for (int j = 0; j < 4; ++j) {                                     \
            acc[I][j] = __builtin_amdgcn_mfma_f32_16x16x32_fp8_fp8(       \
                (LA).x, lb[j].x, acc[I][j], 0, 0, 0);                     \
            acc[I][j] = __builtin_amdgcn_mfma_f32_16x16x32_fp8_fp8(       \
                (LA).y, lb[j].y, acc[I][j], 0, 0, 0);                     \
        }                                                                 \
    } while (0)

#define COMPUTE(buf)                                                      \
    do {                                                                  \
        const unsigned char* s = &sm[buf][0];                             \
        long2_t lb[4];                                                    \
        _Pragma("unroll")                                                 \
        for (int j = 0; j < 4; ++j) lb[j] = *(const long2_t*)(s + boff[j]); \
        long2_t laA = *(const long2_t*)(s + aoff[0]);                     \
        long2_t laB = *(const long2_t*)(s + aoff[1]);                     \
        MFMA8(laA, 0);                                                    \
        laA = *(const long2_t*)(s + aoff[2]);                             \
        MFMA8(laB, 1);                                                    \
        laB = *(const long2_t*)(s + aoff[3]);                             \
        MFMA8(laA, 2);                                                    \
        MFMA8(laB, 3);                                                    \
    } while (0)

    Pref S0, S1;
    LOADSET(S0, 0);
    LOADSET(S1, 1);
    WRITESET(0, S0);        // waits only tile-0 loads (tile-1 stays in flight)
    SYNC_LGKM();

    #pragma unroll
    for (int k = 0; k < NIT - 1; ++k) {
        if (k < NIT - 2) {
            if ((k & 1) == 0) LOADSET(S0, k + 2);
            else              LOADSET(S1, k + 2);
        }
        COMPUTE(k & 1);
        if ((k & 1) == 0) WRITESET(1, S1);
        else              WRITESET(0, S0);
        SYNC_LGKM();
    }
    COMPUTE((NIT - 1) & 1);

    // fp8 partials (x 1/16): per wave 16 frags x 64 lanes, coalesced.
    const int tile = blockIdx.x * 8 + blockIdx.y;     // 0..511
    unsigned int* p = part
        + (((size_t)blockIdx.z * 512 + tile) * 2 + wid) * 1024 + lane;
    #pragma unroll
    for (int i = 0; i < 4; ++i)
        #pragma unroll
        for (int j = 0; j < 4; ++j) {
            unsigned int pk = 0;
            pk = __builtin_amdgcn_cvt_pk_fp8_f32(
                acc[i][j][0] * PSCALE, acc[i][j][1] * PSCALE, pk, false);
            pk = __builtin_amdgcn_cvt_pk_fp8_f32(
                acc[i][j][2] * PSCALE, acc[i][j][3] * PSCALE, pk, true);
            p[(i * 4 + j) * 64] = pk;
        }
#undef LOADSET
#undef WRITESET
#undef MFMA8
#undef COMPUTE
}

// 512 blocks, one per gemm tile. Sums KSPLIT slices (fp8 unpack), applies
// epilogue, scatters to out.
__global__ __launch_bounds__(256) void reduce_out(
    const unsigned int* __restrict__ part, const float* __restrict__ xsq,
    const float* __restrict__ wsq, float* __restrict__ out)
{
    const int tile = blockIdx.x;          // 0..511
    const int t = threadIdx.x;
    const int tm = (tile >> 3) * TM, tn = (tile & 7) * TN;
    const size_t sl = (size_t)512 * 2 * 1024;   // uints per z-slice
    const float c1 = 2.0f * PS_INV * INV_SS / (float)DDIM;
    const float c2 = 1.0f / (float)DDIM;

    #pragma unroll
    for (int s = 0; s < 8; ++s) {
        int u = s * 256 + t;              // 0..2047 within tile
        int uw = u >> 10;                 // wave id
        int uf = (u >> 6) & 15;           // frag id
        int ul = u & 63;                  // lane
        size_t o = ((size_t)tile * 2 + uw) * 1024 + uf * 64 + ul;
        f32x2 s01 = {0.f, 0.f}, s23 = {0.f, 0.f};
        #pragma unroll
        for (int z = 0; z < KSPLIT; ++z) {
            unsigned int v = part[o + (size_t)z * sl];
            s01 += __builtin_amdgcn_cvt_pk_f32_fp8(v, false);
            s23 += __builtin_amdgcn_cvt_pk_f32_fp8(v, true);
        }
        int i = uf >> 2, j = uf & 3;
        int gn = tn + uw * 64 + j * 16 + (ul & 15);
        int gm0 = tm + i * 16 + (ul >> 4) * 4;
        float wv = wsq[gn];
        float sv[4] = {s01.x, s01.y, s23.x, s23.y};
        #pragma unroll
        for (int r = 0; r < 4; ++r)
            out[(size_t)(gm0 + r) * CDIM + gn] = sv[r] * c1 - (xsq[gm0 + r] + wv) * c2;
    }
}

// --- Fallback: naive fp32 (any ws) ---
__global__ void fallback_kernel(const float* __restrict__ x, const float* __restrict__ W,
                                float* __restrict__ out)
{
    int c = blockIdx.x * blockDim.x + threadIdx.x;
    int b = blockIdx.y;
    if (c >= CDIM) return;
    const float* xr = x + (size_t)b * DDIM;
    const float* wr = W + (size_t)c * DDIM;
    float xs = 0.f, ws = 0.f, cr = 0.f;
    for (int d = 0; d < DDIM; ++d) {
        float xv = xr[d], wv = wr[d];
        xs += xv * xv; ws += wv * wv; cr += xv * wv;
    }
    out[(size_t)b * CDIM + c] = (2.0f * cr - xs - ws) / (float)DDIM;
}

extern "C" void kernel_launch(void* const* d_in, const int* in_sizes, int n_in,
                              void* d_out, int out_size, void* d_ws, size_t ws_size,
                              hipStream_t stream) {
    const float* x = (const float*)d_in[0];   // [B, D] fp32
    const float* W = (const float*)d_in[1];   // [C, D] fp32
    float* out = (float*)d_out;               // [B, C] fp32

    size_t need = (size_t)(BDIM + CDIM) * DDIM                 // fp8 inputs 20 MB
                + (size_t)(BDIM + CDIM) * sizeof(float)        // norms
                + (size_t)KSPLIT * BDIM * CDIM;                // fp8 partials 16 MB
    if (ws_size < need) {
        fallback_kernel<<<dim3(CDIM / 256, BDIM), 256, 0, stream>>>(x, W, out);
        return;
    }

    unsigned char* xb = (unsigned char*)d_ws;              // 16 MB
    unsigned char* wb = xb + (size_t)BDIM * DDIM;          // 4 MB
    float* xsq = (float*)(wb + (size_t)CDIM * DDIM);       // 16 KB
    float* wsq = xsq + BDIM;                               // 4 KB
    unsigned int* part = (unsigned int*)(wsq + CDIM);      // 16 MB

    cvt_rowsq<<<(BDIM + CDIM) / 4, 256, 0, stream>>>(x, W, xb, wb, xsq, wsq);
    gemm_eucl<<<dim3(BDIM / TM, CDIM / TN, KSPLIT), 128, 0, stream>>>(xb, wb, part);
    reduce_out<<<512, 256, 0, stream>>>(part, xsq, wsq, out);
}